// Round 2
// baseline (3764.525 us; speedup 1.0000x reference)
//
#include <hip/hip_runtime.h>
#include <hip/hip_bf16.h>
#include <math.h>

// Problem constants
#define BB 16
#define TT 30
#define BT 480      // B*T
#define SEQ 90      // 3*T
#define NROWS 1440  // B*SEQ
#define DMODEL 512
#define DINNER 1024
#define NSTATE 64
#define DTRANK 32
#define NVOCAB 18

__device__ __forceinline__ float sigmoidf_(float x){ return 1.f/(1.f+__expf(-x)); }

// ---------------- Encoder convs (naive direct) ----------------
__global__ __launch_bounds__(256) void conv1_kernel(const float* __restrict__ in,
                                                    const float* __restrict__ w,
                                                    const float* __restrict__ b,
                                                    float* __restrict__ out){
    int idx = blockIdx.x*256 + threadIdx.x;            // 480*32*20*20
    if (idx >= BT*32*20*20) return;
    int ox = idx % 20; int t = idx/20;
    int oy = t % 20;   t /= 20;
    int oc = t % 32;   int img = t/32;
    const float* ip = in + (size_t)img*4*84*84;
    const float* wp = w + oc*4*64;
    float acc = b[oc];
    #pragma unroll
    for (int ic=0; ic<4; ic++){
        const float* ipc = ip + ic*84*84 + (oy*4)*84 + ox*4;
        const float* wpc = wp + ic*64;
        #pragma unroll
        for (int ky=0;ky<8;ky++)
            #pragma unroll
            for (int kx=0;kx<8;kx++)
                acc += ipc[ky*84+kx]*wpc[ky*8+kx];
    }
    out[idx] = fmaxf(acc, 0.f);
}

__global__ __launch_bounds__(256) void conv2_kernel(const float* __restrict__ in,
                                                    const float* __restrict__ w,
                                                    const float* __restrict__ b,
                                                    float* __restrict__ out){
    int idx = blockIdx.x*256 + threadIdx.x;            // 480*64*9*9
    if (idx >= BT*64*81) return;
    int ox = idx % 9; int t = idx/9;
    int oy = t % 9;   t /= 9;
    int oc = t % 64;  int img = t/64;
    const float* ip = in + (size_t)img*32*400;
    const float* wp = w + oc*32*16;
    float acc = b[oc];
    for (int ic=0; ic<32; ic++){
        const float* ipc = ip + ic*400 + (oy*2)*20 + ox*2;
        const float* wpc = wp + ic*16;
        #pragma unroll
        for (int ky=0;ky<4;ky++)
            #pragma unroll
            for (int kx=0;kx<4;kx++)
                acc += ipc[ky*20+kx]*wpc[ky*4+kx];
    }
    out[idx] = fmaxf(acc, 0.f);
}

__global__ __launch_bounds__(256) void conv3_kernel(const float* __restrict__ in,
                                                    const float* __restrict__ w,
                                                    const float* __restrict__ b,
                                                    float* __restrict__ out){
    int idx = blockIdx.x*256 + threadIdx.x;            // 480*64*7*7
    if (idx >= BT*64*49) return;
    int ox = idx % 7; int t = idx/7;
    int oy = t % 7;   t /= 7;
    int oc = t % 64;  int img = t/64;
    const float* ip = in + (size_t)img*64*81;
    const float* wp = w + oc*64*9;
    float acc = b[oc];
    for (int ic=0; ic<64; ic++){
        const float* ipc = ip + ic*81 + oy*9 + ox;
        const float* wpc = wp + ic*9;
        #pragma unroll
        for (int ky=0;ky<3;ky++)
            #pragma unroll
            for (int kx=0;kx<3;kx++)
                acc += ipc[ky*9+kx]*wpc[ky*3+kx];
    }
    out[idx] = fmaxf(acc, 0.f);
}

// ---------------- Generic tiled fp32 GEMM ----------------
// C[M,N] (ldc) = epi(A[M,K] (lda) @ B[K,N] (ldb) + bias)
// ACT: 0 none, 1 tanh, 2 softplus.  ADDC: C += result.
template<bool HAS_BIAS, int ACT, bool ADDC>
__global__ __launch_bounds__(256) void gemm_kernel(const float* __restrict__ A,
                                                   const float* __restrict__ Bm,
                                                   const float* __restrict__ bias,
                                                   float* __restrict__ C,
                                                   int M, int N, int K,
                                                   int lda, int ldb, int ldc){
    const int BM=64, BN=64, BK=16;
    __shared__ float As[BK][BM+1];
    __shared__ float Bs[BK][BN+1];
    int bm = blockIdx.y*BM, bn = blockIdx.x*BN;
    int tid = threadIdx.x;
    int tx = tid & 15, ty = tid >> 4;
    float acc[4][4] = {};
    for (int k0=0; k0<K; k0+=BK){
        #pragma unroll
        for (int i=0;i<4;i++){
            int li = tid + 256*i;
            int r = li>>4, c = li&15;
            int gr = bm + r, gc = k0 + c;
            As[c][r] = (gr<M && gc<K) ? A[(size_t)gr*lda+gc] : 0.f;
        }
        #pragma unroll
        for (int i=0;i<4;i++){
            int li = tid + 256*i;
            int r = li>>6, c = li&63;
            int gr = k0 + r, gc = bn + c;
            Bs[r][c] = (gr<K && gc<N) ? Bm[(size_t)gr*ldb+gc] : 0.f;
        }
        __syncthreads();
        #pragma unroll
        for (int kk=0;kk<BK;kk++){
            float a[4], b[4];
            #pragma unroll
            for (int i=0;i<4;i++) a[i]=As[kk][ty*4+i];
            #pragma unroll
            for (int j=0;j<4;j++) b[j]=Bs[kk][tx*4+j];
            #pragma unroll
            for (int i=0;i<4;i++)
                #pragma unroll
                for (int j=0;j<4;j++)
                    acc[i][j] += a[i]*b[j];
        }
        __syncthreads();
    }
    #pragma unroll
    for (int i=0;i<4;i++){
        int gr = bm + ty*4 + i;
        if (gr>=M) continue;
        #pragma unroll
        for (int j=0;j<4;j++){
            int gc = bn + tx*4 + j;
            if (gc>=N) continue;
            float v = acc[i][j];
            if (HAS_BIAS) v += bias[gc];
            if (ACT==1) v = tanhf(v);
            else if (ACT==2) v = (v>20.f)? v : log1pf(__expf(v));
            if (ADDC) C[(size_t)gr*ldc+gc] += v;
            else      C[(size_t)gr*ldc+gc] = v;
        }
    }
}

// ---------------- Token build ----------------
__global__ __launch_bounds__(256) void tokens_kernel(const float* __restrict__ rtgs,
                                                     const int* __restrict__ actions,
                                                     const float* __restrict__ state_e,
                                                     const float* __restrict__ ret_w,
                                                     const float* __restrict__ ret_b,
                                                     const float* __restrict__ act_emb,
                                                     float* __restrict__ tok){
    int idx = blockIdx.x*256 + threadIdx.x;            // 1440*512
    if (idx >= NROWS*DMODEL) return;
    int e = idx & (DMODEL-1);
    int row = idx >> 9;
    int rr = row % SEQ; int b = row / SEQ;
    int s = rr % 3, t = rr / 3;
    float v;
    if (s==0)       v = tanhf(rtgs[b*TT+t]*ret_w[e] + ret_b[e]);
    else if (s==1)  v = state_e[(size_t)(b*TT+t)*DMODEL + e];
    else            v = tanhf(act_emb[(size_t)actions[b*TT+t]*DMODEL + e]);
    tok[idx] = v;
}

// ---------------- RMSNorm (block per row) ----------------
__global__ __launch_bounds__(256) void rmsnorm_kernel(const float* __restrict__ x,
                                                      const float* __restrict__ w,
                                                      float* __restrict__ o){
    int row = blockIdx.x;
    int tid = threadIdx.x;
    float v0 = x[(size_t)row*DMODEL + tid];
    float v1 = x[(size_t)row*DMODEL + 256 + tid];
    float s = v0*v0 + v1*v1;
    for (int off=32; off; off>>=1) s += __shfl_xor(s, off, 64);
    __shared__ float wsum[4];
    if ((tid&63)==0) wsum[tid>>6] = s;
    __syncthreads();
    s = wsum[0]+wsum[1]+wsum[2]+wsum[3];
    float scale = rsqrtf(s*(1.f/DMODEL) + 1e-5f);
    o[(size_t)row*DMODEL + tid]       = v0*scale*w[tid];
    o[(size_t)row*DMODEL + 256 + tid] = v1*scale*w[256+tid];
}

// final norm: only state-token rows (b*90 + 3t + 1) -> xf[480 rows]
__global__ __launch_bounds__(256) void rmsnorm_final_kernel(const float* __restrict__ x,
                                                            const float* __restrict__ w,
                                                            float* __restrict__ o){
    int r = blockIdx.x;              // 0..479 = b*30+t
    int b = r / TT, t = r % TT;
    int src = b*SEQ + 3*t + 1;
    int tid = threadIdx.x;
    float v0 = x[(size_t)src*DMODEL + tid];
    float v1 = x[(size_t)src*DMODEL + 256 + tid];
    float s = v0*v0 + v1*v1;
    for (int off=32; off; off>>=1) s += __shfl_xor(s, off, 64);
    __shared__ float wsum[4];
    if ((tid&63)==0) wsum[tid>>6] = s;
    __syncthreads();
    s = wsum[0]+wsum[1]+wsum[2]+wsum[3];
    float scale = rsqrtf(s*(1.f/DMODEL) + 1e-5f);
    o[(size_t)r*DMODEL + tid]       = v0*scale*w[tid];
    o[(size_t)r*DMODEL + 256 + tid] = v1*scale*w[256+tid];
}

// ---------------- Depthwise causal conv (K=4) + SiLU ----------------
__global__ __launch_bounds__(256) void dwconv_silu_kernel(const float* __restrict__ xz,
                                                          const float* __restrict__ cw,
                                                          const float* __restrict__ cb,
                                                          float* __restrict__ u){
    int idx = blockIdx.x*256 + threadIdx.x;            // 1440*1024
    if (idx >= NROWS*DINNER) return;
    int d = idx & (DINNER-1);
    int row = idx >> 10;
    int t = row % SEQ;
    int b = row / SEQ;
    float acc = cb[d];
    const float* w = cw + d*4;
    #pragma unroll
    for (int k=0;k<4;k++){
        int ts = t - 3 + k;
        if (ts >= 0)
            acc += w[k]*xz[(size_t)(b*SEQ+ts)*(2*DINNER) + d];
    }
    u[idx] = acc*sigmoidf_(acc);
}

// ---------------- Selective scan (one wave per (b,d), lane = n) ----------------
__global__ __launch_bounds__(64) void scan_kernel(const float* __restrict__ delta, // (1440,1024)
                                                  const float* __restrict__ u,     // (1440,1024)
                                                  const float* __restrict__ xdbl,  // (1440,160)
                                                  const float* __restrict__ alog,  // (1024,64)
                                                  const float* __restrict__ Dp,    // (1024)
                                                  const float* __restrict__ xz,    // (1440,2048) res part
                                                  float* __restrict__ yout){       // (1440,1024)
    int blk = blockIdx.x;            // 16*1024
    int d = blk & (DINNER-1);
    int b = blk >> 10;
    int lane = threadIdx.x;
    float A = -__expf(alog[(size_t)d*NSTATE + lane]);
    float Dv = Dp[d];
    float h = 0.f;
    int base = b*SEQ;
    for (int t=0;t<SEQ;t++){
        int row = base + t;
        float dt = delta[(size_t)row*DINNER + d];
        float uu = u[(size_t)row*DINNER + d];
        float Bv = xdbl[row*160 + DTRANK + lane];
        float Cv = xdbl[row*160 + DTRANK + NSTATE + lane];
        float dA = __expf(dt*A);
        h = dA*h + dt*uu*Bv;
        float p = h*Cv;
        #pragma unroll
        for (int off=32; off; off>>=1) p += __shfl_xor(p, off, 64);
        if (lane==0){
            float res = xz[(size_t)row*(2*DINNER) + DINNER + d];
            yout[(size_t)row*DINNER + d] = (p + uu*Dv) * (res*sigmoidf_(res));
        }
    }
}

// ---------------- Head: logits for state-token rows ----------------
__global__ __launch_bounds__(256) void head_kernel(const float* __restrict__ xf,   // (480,512)
                                                   const float* __restrict__ hw,   // (512,18)
                                                   float* __restrict__ out){       // (480,18)
    int idx = blockIdx.x*256 + threadIdx.x;
    if (idx >= BT*NVOCAB) return;
    int col = idx % NVOCAB, r = idx / NVOCAB;
    const float* xr = xf + (size_t)r*DMODEL;
    float acc = 0.f;
    for (int k=0;k<DMODEL;k++) acc += xr[k]*hw[k*NVOCAB+col];
    out[idx] = acc;
}

extern "C" void kernel_launch(void* const* d_in, const int* in_sizes, int n_in,
                              void* d_out, int out_size, void* d_ws, size_t ws_size,
                              hipStream_t stream) {
    const float* states = (const float*)d_in[0];
    const int*   actions= (const int*)d_in[1];
    const float* rtgs   = (const float*)d_in[2];
    const float* c1w = (const float*)d_in[3];
    const float* c1b = (const float*)d_in[4];
    const float* c2w = (const float*)d_in[5];
    const float* c2b = (const float*)d_in[6];
    const float* c3w = (const float*)d_in[7];
    const float* c3b = (const float*)d_in[8];
    const float* fcw = (const float*)d_in[9];
    const float* fcb = (const float*)d_in[10];
    const float* retw= (const float*)d_in[11];
    const float* retb= (const float*)d_in[12];
    const float* actemb=(const float*)d_in[13];
    const float* embw= (const float*)d_in[14];
    const float* embb= (const float*)d_in[15];
    const float* normw=(const float*)d_in[16];
    const float* ipw = (const float*)d_in[17];
    const float* cw  = (const float*)d_in[18];
    const float* cb  = (const float*)d_in[19];
    const float* xpw = (const float*)d_in[20];
    const float* dpw = (const float*)d_in[21];
    const float* dpb = (const float*)d_in[22];
    const float* alog= (const float*)d_in[23];
    const float* Dp  = (const float*)d_in[24];
    const float* opw = (const float*)d_in[25];
    const float* normfw=(const float*)d_in[26];
    const float* headw= (const float*)d_in[27];
    float* out = (float*)d_out;

    float* ws = (float*)d_ws;
    // encoder phase buffers
    float* c1   = ws + 0;          // 6,144,000
    float* c2   = ws + 6144000;    // 2,488,320
    float* c3   = ws + 8632320;    // 1,505,280
    float* se   = ws + 10137600;   //   245,760  (alive until tokens)
    // layer phase buffers (reuse encoder region, se excluded)
    float* tok  = ws + 0;          //   737,280  (dead after embed)
    float* xf   = ws + 0;          //   245,760  (tail phase)
    float* x    = ws + 737280;     //   737,280
    float* xn   = ws + 1474560;    //   737,280
    float* xz   = ws + 2211840;    // 2,949,120
    float* u    = ws + 5160960;    // 1,474,560
    float* xdbl = ws + 6635520;    //   230,400
    float* delta= ws + 6865920;    // 1,474,560
    float* y    = ws + 8340480;    // 1,474,560  (ends 9,815,040 < se)

    // ---- encoder ----
    conv1_kernel<<<(BT*32*400+255)/256, 256, 0, stream>>>(states, c1w, c1b, c1);
    conv2_kernel<<<(BT*64*81+255)/256, 256, 0, stream>>>(c1, c2w, c2b, c2);
    conv3_kernel<<<(BT*64*49+255)/256, 256, 0, stream>>>(c2, c3w, c3b, c3);
    // FC + tanh : (480,3136)@(3136,512)
    gemm_kernel<true,1,false><<<dim3(8,8), 256, 0, stream>>>(c3, fcw, fcb, se,
                                                             BT, DMODEL, 3136, 3136, DMODEL, DMODEL);
    // ---- tokens + embedding ----
    tokens_kernel<<<(NROWS*DMODEL+255)/256, 256, 0, stream>>>(rtgs, actions, se, retw, retb, actemb, tok);
    gemm_kernel<true,0,false><<<dim3(8,23), 256, 0, stream>>>(tok, embw, embb, x,
                                                              NROWS, DMODEL, DMODEL, DMODEL, DMODEL, DMODEL);
    // ---- mamba layers ----
    for (int i=0;i<3;i++){
        rmsnorm_kernel<<<NROWS, 256, 0, stream>>>(x, normw + (size_t)i*DMODEL, xn);
        // in_proj: (1440,512)@(512,2048)
        gemm_kernel<false,0,false><<<dim3(32,23), 256, 0, stream>>>(xn, ipw + (size_t)i*DMODEL*2*DINNER, nullptr, xz,
                                                                    NROWS, 2*DINNER, DMODEL, DMODEL, 2*DINNER, 2*DINNER);
        dwconv_silu_kernel<<<(NROWS*DINNER+255)/256, 256, 0, stream>>>(xz, cw + (size_t)i*DINNER*4, cb + (size_t)i*DINNER, u);
        // x_proj: (1440,1024)@(1024,160)
        gemm_kernel<false,0,false><<<dim3(3,23), 256, 0, stream>>>(u, xpw + (size_t)i*DINNER*160, nullptr, xdbl,
                                                                   NROWS, 160, DINNER, DINNER, 160, 160);
        // dt_proj + softplus: (1440,32)@(32,1024), A view of xdbl with lda=160
        gemm_kernel<true,2,false><<<dim3(16,23), 256, 0, stream>>>(xdbl, dpw + (size_t)i*DTRANK*DINNER, dpb + (size_t)i*DINNER, delta,
                                                                   NROWS, DINNER, DTRANK, 160, DINNER, DINNER);
        scan_kernel<<<BB*DINNER, 64, 0, stream>>>(delta, u, xdbl,
                                                  alog + (size_t)i*DINNER*NSTATE,
                                                  Dp + (size_t)i*DINNER, xz, y);
        // out_proj with residual add: x += (1440,1024)@(1024,512)
        gemm_kernel<false,0,true><<<dim3(8,23), 256, 0, stream>>>(y, opw + (size_t)i*DINNER*DMODEL, nullptr, x,
                                                                  NROWS, DMODEL, DINNER, DINNER, DMODEL, DMODEL);
    }
    // ---- final norm (state rows only) + head ----
    rmsnorm_final_kernel<<<BT, 256, 0, stream>>>(x, normfw, xf);
    head_kernel<<<(BT*NVOCAB+255)/256, 256, 0, stream>>>(xf, headw, out);
}

// Round 6
// 1918.644 us; speedup vs baseline: 1.9621x; 1.9621x over previous
//
#include <hip/hip_runtime.h>
#include <hip/hip_bf16.h>
#include <math.h>

// Problem constants
#define BB 16
#define TT 30
#define BT 480      // B*T
#define SEQ 90      // 3*T
#define NROWS 1440  // B*SEQ
#define DMODEL 512
#define DINNER 1024
#define NSTATE 64
#define DTRANK 32
#define NVOCAB 18

typedef __attribute__((ext_vector_type(8))) short short8;
typedef __attribute__((ext_vector_type(4))) float f32x4;

__device__ __forceinline__ float sigmoidf_(float x){ return 1.f/(1.f+__expf(-x)); }
__device__ __forceinline__ ushort f2bf(float f){
    union { float f; uint32_t u; } v; v.f = f;
    uint32_t r = v.u + 0x7FFFu + ((v.u >> 16) & 1u);   // RNE
    return (ushort)(r >> 16);
}

// ---------------- Encoder convs (naive direct) ----------------
__global__ __launch_bounds__(256) void conv1_kernel(const float* __restrict__ in,
                                                    const float* __restrict__ w,
                                                    const float* __restrict__ b,
                                                    float* __restrict__ out){
    int idx = blockIdx.x*256 + threadIdx.x;            // 480*32*20*20
    if (idx >= BT*32*20*20) return;
    int ox = idx % 20; int t = idx/20;
    int oy = t % 20;   t /= 20;
    int oc = t % 32;   int img = t/32;
    const float* ip = in + (size_t)img*4*84*84;
    const float* wp = w + oc*4*64;
    float acc = b[oc];
    #pragma unroll
    for (int ic=0; ic<4; ic++){
        const float* ipc = ip + ic*84*84 + (oy*4)*84 + ox*4;
        const float* wpc = wp + ic*64;
        #pragma unroll
        for (int ky=0;ky<8;ky++)
            #pragma unroll
            for (int kx=0;kx<8;kx++)
                acc += ipc[ky*84+kx]*wpc[ky*8+kx];
    }
    out[idx] = fmaxf(acc, 0.f);
}

__global__ __launch_bounds__(256) void conv2_kernel(const float* __restrict__ in,
                                                    const float* __restrict__ w,
                                                    const float* __restrict__ b,
                                                    float* __restrict__ out){
    int idx = blockIdx.x*256 + threadIdx.x;            // 480*64*9*9
    if (idx >= BT*64*81) return;
    int ox = idx % 9; int t = idx/9;
    int oy = t % 9;   t /= 9;
    int oc = t % 64;  int img = t/64;
    const float* ip = in + (size_t)img*32*400;
    const float* wp = w + oc*32*16;
    float acc = b[oc];
    for (int ic=0; ic<32; ic++){
        const float* ipc = ip + ic*400 + (oy*2)*20 + ox*2;
        const float* wpc = wp + ic*16;
        #pragma unroll
        for (int ky=0;ky<4;ky++)
            #pragma unroll
            for (int kx=0;kx<4;kx++)
                acc += ipc[ky*20+kx]*wpc[ky*4+kx];
    }
    out[idx] = fmaxf(acc, 0.f);
}

__global__ __launch_bounds__(256) void conv3_kernel(const float* __restrict__ in,
                                                    const float* __restrict__ w,
                                                    const float* __restrict__ b,
                                                    float* __restrict__ out){
    int idx = blockIdx.x*256 + threadIdx.x;            // 480*64*7*7
    if (idx >= BT*64*49) return;
    int ox = idx % 7; int t = idx/7;
    int oy = t % 7;   t /= 7;
    int oc = t % 64;  int img = t/64;
    const float* ip = in + (size_t)img*64*81;
    const float* wp = w + oc*64*9;
    float acc = b[oc];
    for (int ic=0; ic<64; ic++){
        const float* ipc = ip + ic*81 + oy*9 + ox;
        const float* wpc = wp + ic*9;
        #pragma unroll
        for (int ky=0;ky<3;ky++)
            #pragma unroll
            for (int kx=0;kx<3;kx++)
                acc += ipc[ky*9+kx]*wpc[ky*3+kx];
    }
    out[idx] = fmaxf(acc, 0.f);
}

// ---------------- Weight prep: fp32 -> bf16 transposed [N][K] ----------------
__global__ __launch_bounds__(256) void prep_fc_emb(const float* __restrict__ fcw,   // (3136,512)
                                                   const float* __restrict__ embw,  // (512,512)
                                                   ushort* __restrict__ fct,        // (512,3136) bf16
                                                   ushort* __restrict__ embt){      // (512,512) bf16
    int idx = blockIdx.x*256 + threadIdx.x;
    const int FCE = 3136*512;
    if (idx < FCE){
        int n = idx / 3136, k = idx - n*3136;
        fct[idx] = f2bf(fcw[(size_t)k*512 + n]);
    } else {
        int r = idx - FCE;
        if (r < 512*512){
            int n = r >> 9, k = r & 511;
            embt[r] = f2bf(embw[(size_t)k*512 + n]);
        }
    }
}

// Per-layer block layout (bf16 elems): [ip_t 1048576 | xp_t 163840 | dt_t 32768 | op_t 524288]
#define WT_PER 1769472
__global__ __launch_bounds__(256) void prep_layers(const float* __restrict__ ipw,  // (L,512,2048)
                                                   const float* __restrict__ xpw,  // (L,1024,160)
                                                   const float* __restrict__ dpw,  // (L,32,1024)
                                                   const float* __restrict__ opw,  // (L,1024,512)
                                                   ushort* __restrict__ wt){
    int idx = blockIdx.x*256 + threadIdx.x;
    if (idx >= 3*WT_PER) return;
    int layer = idx / WT_PER;
    int r = idx - layer*WT_PER;
    ushort* dst = wt + (size_t)layer*WT_PER;
    if (r < 1048576){                       // ip: K=512, N=2048, src stride 2048
        int n = r >> 9, k = r & 511;
        dst[r] = f2bf(ipw[(size_t)layer*1048576 + (size_t)k*2048 + n]);
    } else if (r < 1212416){                // xp: K=1024, N=160, src stride 160
        int q = r - 1048576;
        int n = q >> 10, k = q & 1023;
        dst[r] = f2bf(xpw[(size_t)layer*163840 + (size_t)k*160 + n]);
    } else if (r < 1245184){                // dt: K=32, N=1024, src stride 1024
        int q = r - 1212416;
        int n = q >> 5, k = q & 31;
        dst[r] = f2bf(dpw[(size_t)layer*32768 + (size_t)k*1024 + n]);
    } else {                                // op: K=1024, N=512, src stride 512  (FIXED: was k*1024)
        int q = r - 1245184;
        int n = q >> 10, k = q & 1023;
        dst[r] = f2bf(opw[(size_t)layer*524288 + (size_t)k*512 + n]);
    }
}

// ---------------- bf16 MFMA GEMM ----------------
// C[M,N] = epi(A[M,K] (fp32, lda) @ Bt[N,K] (bf16) + bias)
// Block: 256 thr = 4 waves (2x2), tile 64x64, wave tile 32x32, BK=32.
// ACT: 0 none, 1 tanh, 2 softplus.  ADDC: C += result.
template<bool HAS_BIAS, int ACT, bool ADDC>
__global__ __launch_bounds__(256) void mgemm_kernel(const float* __restrict__ A,
                                                    const ushort* __restrict__ Bt,
                                                    const float* __restrict__ bias,
                                                    float* __restrict__ C,
                                                    int M, int N, int K,
                                                    int lda, int ldc){
    __shared__ __align__(16) ushort As[64][32];
    __shared__ __align__(16) ushort Bs[64][32];
    int bm = blockIdx.y*64, bn = blockIdx.x*64;
    int tid = threadIdx.x;
    int w = tid >> 6, lane = tid & 63;
    int wm = (w >> 1)*32, wn = (w & 1)*32;
    int lr = lane & 15, lg8 = (lane >> 4)*8;
    // staging assignment: each thread = one (row, 8-elem k-chunk)
    int sm  = tid >> 2;           // 0..63
    int skq = (tid & 3) * 8;      // 0,8,16,24
    int gm = bm + sm;
    int gn = bn + sm;
    bool mok = (gm < M);
    bool nok = (gn < N);
    const float*  arow_p = A  + (size_t)(mok ? gm : 0)*lda + skq;
    const ushort* brow_p = Bt + (size_t)(nok ? gn : 0)*K   + skq;
    f32x4 acc[2][2] = {};
    for (int k0 = 0; k0 < K; k0 += 32){
        // stage A (fp32 -> bf16), built directly as a vector
        short8 av = {0,0,0,0,0,0,0,0};
        if (mok){
            const float* p = arow_p + k0;
            #pragma unroll
            for (int j=0;j<8;j++) av[j] = (short)f2bf(p[j]);
        }
        *reinterpret_cast<short8*>(&As[sm][skq]) = av;
        // stage B (already bf16)
        short8 bv = {0,0,0,0,0,0,0,0};
        if (nok) bv = *reinterpret_cast<const short8*>(brow_p + k0);
        *reinterpret_cast<short8*>(&Bs[sm][skq]) = bv;
        __syncthreads();
        short8 af0 = *reinterpret_cast<const short8*>(&As[wm + lr][lg8]);
        short8 af1 = *reinterpret_cast<const short8*>(&As[wm + 16 + lr][lg8]);
        short8 bf0 = *reinterpret_cast<const short8*>(&Bs[wn + lr][lg8]);
        short8 bf1 = *reinterpret_cast<const short8*>(&Bs[wn + 16 + lr][lg8]);
        acc[0][0] = __builtin_amdgcn_mfma_f32_16x16x32_bf16(af0, bf0, acc[0][0], 0,0,0);
        acc[0][1] = __builtin_amdgcn_mfma_f32_16x16x32_bf16(af0, bf1, acc[0][1], 0,0,0);
        acc[1][0] = __builtin_amdgcn_mfma_f32_16x16x32_bf16(af1, bf0, acc[1][0], 0,0,0);
        acc[1][1] = __builtin_amdgcn_mfma_f32_16x16x32_bf16(af1, bf1, acc[1][1], 0,0,0);
        __syncthreads();
    }
    // epilogue: C/D layout col=lane&15, row=(lane>>4)*4+reg
    int lg4 = (lane >> 4) * 4;
    #pragma unroll
    for (int i=0;i<2;i++){
        #pragma unroll
        for (int j=0;j<2;j++){
            int gcol = bn + wn + j*16 + lr;
            if (gcol >= N) continue;
            float bval = HAS_BIAS ? bias[gcol] : 0.f;
            #pragma unroll
            for (int r=0;r<4;r++){
                int grow = bm + wm + i*16 + lg4 + r;
                if (grow >= M) continue;
                float v = acc[i][j][r] + bval;
                if (ACT==1) v = tanhf(v);
                else if (ACT==2) v = (v>20.f)? v : log1pf(__expf(v));
                if (ADDC) C[(size_t)grow*ldc + gcol] += v;
                else      C[(size_t)grow*ldc + gcol] = v;
            }
        }
    }
}

// ---------------- Token build ----------------
__global__ __launch_bounds__(256) void tokens_kernel(const float* __restrict__ rtgs,
                                                     const int* __restrict__ actions,
                                                     const float* __restrict__ state_e,
                                                     const float* __restrict__ ret_w,
                                                     const float* __restrict__ ret_b,
                                                     const float* __restrict__ act_emb,
                                                     float* __restrict__ tok){
    int idx = blockIdx.x*256 + threadIdx.x;            // 1440*512
    if (idx >= NROWS*DMODEL) return;
    int e = idx & (DMODEL-1);
    int row = idx >> 9;
    int rr = row % SEQ; int b = row / SEQ;
    int s = rr % 3, t = rr / 3;
    float v;
    if (s==0)       v = tanhf(rtgs[b*TT+t]*ret_w[e] + ret_b[e]);
    else if (s==1)  v = state_e[(size_t)(b*TT+t)*DMODEL + e];
    else            v = tanhf(act_emb[(size_t)actions[b*TT+t]*DMODEL + e]);
    tok[idx] = v;
}

// ---------------- RMSNorm (block per row) ----------------
__global__ __launch_bounds__(256) void rmsnorm_kernel(const float* __restrict__ x,
                                                      const float* __restrict__ w,
                                                      float* __restrict__ o){
    int row = blockIdx.x;
    int tid = threadIdx.x;
    float v0 = x[(size_t)row*DMODEL + tid];
    float v1 = x[(size_t)row*DMODEL + 256 + tid];
    float s = v0*v0 + v1*v1;
    for (int off=32; off; off>>=1) s += __shfl_xor(s, off, 64);
    __shared__ float wsum[4];
    if ((tid&63)==0) wsum[tid>>6] = s;
    __syncthreads();
    s = wsum[0]+wsum[1]+wsum[2]+wsum[3];
    float scale = rsqrtf(s*(1.f/DMODEL) + 1e-5f);
    o[(size_t)row*DMODEL + tid]       = v0*scale*w[tid];
    o[(size_t)row*DMODEL + 256 + tid] = v1*scale*w[256+tid];
}

// final norm: only state-token rows (b*90 + 3t + 1) -> xf[480 rows]
__global__ __launch_bounds__(256) void rmsnorm_final_kernel(const float* __restrict__ x,
                                                            const float* __restrict__ w,
                                                            float* __restrict__ o){
    int r = blockIdx.x;              // 0..479 = b*30+t
    int b = r / TT, t = r % TT;
    int src = b*SEQ + 3*t + 1;
    int tid = threadIdx.x;
    float v0 = x[(size_t)src*DMODEL + tid];
    float v1 = x[(size_t)src*DMODEL + 256 + tid];
    float s = v0*v0 + v1*v1;
    for (int off=32; off; off>>=1) s += __shfl_xor(s, off, 64);
    __shared__ float wsum[4];
    if ((tid&63)==0) wsum[tid>>6] = s;
    __syncthreads();
    s = wsum[0]+wsum[1]+wsum[2]+wsum[3];
    float scale = rsqrtf(s*(1.f/DMODEL) + 1e-5f);
    o[(size_t)r*DMODEL + tid]       = v0*scale*w[tid];
    o[(size_t)r*DMODEL + 256 + tid] = v1*scale*w[256+tid];
}

// ---------------- Depthwise causal conv (K=4) + SiLU, IN-PLACE on xs half of xz ----------------
// One thread per (b,d); walks t serially with a register window -> safe in-place.
__global__ __launch_bounds__(256) void dwconv_silu_inplace(float* __restrict__ xz,
                                                           const float* __restrict__ cw,
                                                           const float* __restrict__ cb){
    int idx = blockIdx.x*256 + threadIdx.x;            // 16*1024
    if (idx >= BB*DINNER) return;
    int d = idx & (DINNER-1);
    int b = idx >> 10;
    float w0 = cw[d*4+0], w1 = cw[d*4+1], w2 = cw[d*4+2], w3 = cw[d*4+3];
    float bias = cb[d];
    float xm3 = 0.f, xm2 = 0.f, xm1 = 0.f;
    float* p = xz + (size_t)(b*SEQ)*(2*DINNER) + d;
    for (int t=0;t<SEQ;t++){
        float cur = p[(size_t)t*(2*DINNER)];
        float acc = bias + w0*xm3 + w1*xm2 + w2*xm1 + w3*cur;
        p[(size_t)t*(2*DINNER)] = acc*sigmoidf_(acc);
        xm3 = xm2; xm2 = xm1; xm1 = cur;
    }
}

// ---------------- Selective scan (one wave per (b,d), lane = n), y in-place over delta ----------------
__global__ __launch_bounds__(64) void scan_kernel(float* delta_y,                  // (1440,1024) in: delta, out: y
                                                  const float* __restrict__ xz,    // (1440,2048): u = cols[0,1024), res = cols[1024,2048)
                                                  const float* __restrict__ xdbl,  // (1440,160)
                                                  const float* __restrict__ alog,  // (1024,64)
                                                  const float* __restrict__ Dp){   // (1024)
    int blk = blockIdx.x;            // 16*1024
    int d = blk & (DINNER-1);
    int b = blk >> 10;
    int lane = threadIdx.x;
    float A = -__expf(alog[(size_t)d*NSTATE + lane]);
    float Dv = Dp[d];
    float h = 0.f;
    int base = b*SEQ;
    for (int t=0;t<SEQ;t++){
        int row = base + t;
        float dt = delta_y[(size_t)row*DINNER + d];
        float uu = xz[(size_t)row*(2*DINNER) + d];
        float Bv = xdbl[row*160 + DTRANK + lane];
        float Cv = xdbl[row*160 + DTRANK + NSTATE + lane];
        float dA = __expf(dt*A);
        h = dA*h + dt*uu*Bv;
        float p = h*Cv;
        #pragma unroll
        for (int off=32; off; off>>=1) p += __shfl_xor(p, off, 64);
        if (lane==0){
            float res = xz[(size_t)row*(2*DINNER) + DINNER + d];
            delta_y[(size_t)row*DINNER + d] = (p + uu*Dv) * (res*sigmoidf_(res));
        }
    }
}

// ---------------- Head: logits for state-token rows ----------------
__global__ __launch_bounds__(256) void head_kernel(const float* __restrict__ xf,   // (480,512)
                                                   const float* __restrict__ hw,   // (512,18)
                                                   float* __restrict__ out){       // (480,18)
    int idx = blockIdx.x*256 + threadIdx.x;
    if (idx >= BT*NVOCAB) return;
    int col = idx % NVOCAB, r = idx / NVOCAB;
    const float* xr = xf + (size_t)r*DMODEL;
    float acc = 0.f;
    for (int k=0;k<DMODEL;k++) acc += xr[k]*hw[k*NVOCAB+col];
    out[idx] = acc;
}

extern "C" void kernel_launch(void* const* d_in, const int* in_sizes, int n_in,
                              void* d_out, int out_size, void* d_ws, size_t ws_size,
                              hipStream_t stream) {
    const float* states = (const float*)d_in[0];
    const int*   actions= (const int*)d_in[1];
    const float* rtgs   = (const float*)d_in[2];
    const float* c1w = (const float*)d_in[3];
    const float* c1b = (const float*)d_in[4];
    const float* c2w = (const float*)d_in[5];
    const float* c2b = (const float*)d_in[6];
    const float* c3w = (const float*)d_in[7];
    const float* c3b = (const float*)d_in[8];
    const float* fcw = (const float*)d_in[9];
    const float* fcb = (const float*)d_in[10];
    const float* retw= (const float*)d_in[11];
    const float* retb= (const float*)d_in[12];
    const float* actemb=(const float*)d_in[13];
    const float* embw= (const float*)d_in[14];
    const float* embb= (const float*)d_in[15];
    const float* normw=(const float*)d_in[16];
    const float* ipw = (const float*)d_in[17];
    const float* cw  = (const float*)d_in[18];
    const float* cb  = (const float*)d_in[19];
    const float* xpw = (const float*)d_in[20];
    const float* dpw = (const float*)d_in[21];
    const float* dpb = (const float*)d_in[22];
    const float* alog= (const float*)d_in[23];
    const float* Dp  = (const float*)d_in[24];
    const float* opw = (const float*)d_in[25];
    const float* normfw=(const float*)d_in[26];
    const float* headw= (const float*)d_in[27];
    float* out = (float*)d_out;

    float* ws = (float*)d_ws;
    // ---- Workspace map (float offsets). TOTAL = 10,268,672 floats = 41.07 MB,
    //      UNDER the round-2-proven ws bound of 10,383,360 floats (41.5 MB). ----
    // Persistent / layer-phase:
    ushort* wt  = (ushort*)(ws + 0);         // [0, 2,654,208)  3*WT_PER bf16
    float* x    = ws + 2654208;    // [2,654,208, 3,391,488)
    float* xn   = ws + 3391488;    // [3,391,488, 4,128,768)  (tok/xf share)
    float* tok  = ws + 3391488;
    float* xf   = ws + 3391488;
    float* xz   = ws + 4128768;    // [4,128,768, 7,077,888)  (u lives in xs half after dwconv)
    float* xdbl = ws + 7077888;    // [7,077,888, 7,308,288)
    float* delta= ws + 7308288;    // [7,308,288, 8,782,848)  (y in-place)
    // Encoder-phase overlays (dead before the overlapping layer-phase writes):
    float* c1   = ws + 0;          // [0, 6,144,000)          dead after conv2
    float* c2   = ws + 6144000;    // [6,144,000, 8,632,320)  dead after conv3
    float* c3   = ws + 8632320;    // [8,632,320, 10,137,600) dead after FC gemm
    ushort* fct  = (ushort*)(ws + 2654208);  // in dead-c1, dead after FC gemm (before x write)
    ushort* embt = (ushort*)(ws + 10137600); // [10,137,600, 10,268,672) dead after emb gemm
    float* se   = ws + 4128768;    // in dead-c1 (xz slot), dead after tokens

    // ---- encoder ----
    conv1_kernel<<<(BT*32*400+255)/256, 256, 0, stream>>>(states, c1w, c1b, c1);
    conv2_kernel<<<(BT*64*81+255)/256, 256, 0, stream>>>(c1, c2w, c2b, c2);
    // c1 dead: prep weights into its region
    prep_fc_emb<<<(3136*512 + 512*512 + 255)/256, 256, 0, stream>>>(fcw, embw, fct, embt);
    prep_layers<<<(3*WT_PER+255)/256, 256, 0, stream>>>(ipw, xpw, dpw, opw, wt);
    conv3_kernel<<<(BT*64*49+255)/256, 256, 0, stream>>>(c2, c3w, c3b, c3);
    // FC + tanh : (480,3136)@(3136,512)
    mgemm_kernel<true,1,false><<<dim3(8,8), 256, 0, stream>>>(c3, fct, fcb, se,
                                                              BT, DMODEL, 3136, 3136, DMODEL);
    // ---- tokens + embedding ----
    tokens_kernel<<<(NROWS*DMODEL+255)/256, 256, 0, stream>>>(rtgs, actions, se, retw, retb, actemb, tok);
    mgemm_kernel<true,0,false><<<dim3(8,23), 256, 0, stream>>>(tok, embt, embb, x,
                                                               NROWS, DMODEL, DMODEL, DMODEL, DMODEL);
    // ---- mamba layers ----
    for (int i=0;i<3;i++){
        const ushort* wl = wt + (size_t)i*WT_PER;
        rmsnorm_kernel<<<NROWS, 256, 0, stream>>>(x, normw + (size_t)i*DMODEL, xn);
        // in_proj: (1440,512)@(512,2048)
        mgemm_kernel<false,0,false><<<dim3(32,23), 256, 0, stream>>>(xn, wl, nullptr, xz,
                                                                     NROWS, 2*DINNER, DMODEL, DMODEL, 2*DINNER);
        // dwconv + SiLU in-place on xs half of xz
        dwconv_silu_inplace<<<(BB*DINNER+255)/256, 256, 0, stream>>>(xz, cw + (size_t)i*DINNER*4, cb + (size_t)i*DINNER);
        // x_proj: (1440,1024)@(1024,160), A = u half of xz (lda=2048)
        mgemm_kernel<false,0,false><<<dim3(3,23), 256, 0, stream>>>(xz, wl + 1048576, nullptr, xdbl,
                                                                    NROWS, 160, DINNER, 2*DINNER, 160);
        // dt_proj + softplus: (1440,32)@(32,1024), A = xdbl view with lda=160
        mgemm_kernel<true,2,false><<<dim3(16,23), 256, 0, stream>>>(xdbl, wl + 1212416, dpb + (size_t)i*DINNER, delta,
                                                                    NROWS, DINNER, DTRANK, 160, DINNER);
        // scan: y overwrites delta
        scan_kernel<<<BB*DINNER, 64, 0, stream>>>(delta, xz, xdbl,
                                                  alog + (size_t)i*DINNER*NSTATE,
                                                  Dp + (size_t)i*DINNER);
        // out_proj with residual add: x += (1440,1024)@(1024,512)
        mgemm_kernel<false,0,true><<<dim3(8,23), 256, 0, stream>>>(delta, wl + 1245184, nullptr, x,
                                                                   NROWS, DMODEL, DINNER, DINNER, DMODEL);
    }
    // ---- final norm (state rows only) + head ----
    rmsnorm_final_kernel<<<BT, 256, 0, stream>>>(x, normfw, xf);
    head_kernel<<<(BT*NVOCAB+255)/256, 256, 0, stream>>>(xf, headw, out);
}

// Round 10
// 1183.376 us; speedup vs baseline: 3.1812x; 1.6213x over previous
//
#include <hip/hip_runtime.h>
#include <hip/hip_bf16.h>
#include <math.h>

// Problem constants
#define BB 16
#define TT 30
#define BT 480      // B*T
#define SEQ 90      // 3*T
#define NROWS 1440  // B*SEQ
#define DMODEL 512
#define DINNER 1024
#define NSTATE 64
#define DTRANK 32
#define NVOCAB 18

typedef __attribute__((ext_vector_type(8))) short short8;
typedef __attribute__((ext_vector_type(4))) short short4v;
typedef __attribute__((ext_vector_type(4))) float f32x4;
typedef __attribute__((ext_vector_type(16))) float f32x16;

__device__ __forceinline__ float sigmoidf_(float x){ return 1.f/(1.f+__expf(-x)); }
__device__ __forceinline__ ushort f2bf(float f){
    union { float f; uint32_t u; } v; v.f = f;
    uint32_t r = v.u + 0x7FFFu + ((v.u >> 16) & 1u);   // RNE
    return (ushort)(r >> 16);
}

// ---------------- Conv weight prep -> bf16, MFMA-friendly K order ----------------
// c1wb[oc][k], k = ic*64+ky*8+kx  (flat OIHW -> direct copy)      8192
// c2wb[oc][k], k = ky*128+ic*4+kx (reordered)                     32768
// c3wb[oc][k], k = ic*9+ky*3+kx   (flat OIHW -> direct copy)      36864
__global__ __launch_bounds__(256) void prep_convw(const float* __restrict__ c1w,
                                                  const float* __restrict__ c2w,
                                                  const float* __restrict__ c3w,
                                                  ushort* __restrict__ c1wb,
                                                  ushort* __restrict__ c2wb,
                                                  ushort* __restrict__ c3wb){
    int idx = blockIdx.x*256 + threadIdx.x;
    if (idx < 8192){
        c1wb[idx] = f2bf(c1w[idx]);
    } else if (idx < 8192 + 32768){
        int q = idx - 8192;
        int oc = q >> 9, k = q & 511;
        int ky = k >> 7, r = k & 127, ic = r >> 2, kx = r & 3;
        c2wb[q] = f2bf(c2w[oc*512 + ic*16 + ky*4 + kx]);
    } else if (idx < 77824){
        int q = idx - 40960;
        c3wb[q] = f2bf(c3w[q]);
    }
}

// ---------------- conv1: 8x8 s4, 4ch -> 32oc, 84x84 -> 20x20, fused im2col MFMA ----------------
// Block = (img, oy-half). M=200 pixels (pad 224), N=32, K=256 (16 k-steps).
__global__ __launch_bounds__(256) void conv1_mfma(const float* __restrict__ in,
                                                  const ushort* __restrict__ wb,
                                                  const float* __restrict__ bias,
                                                  float* __restrict__ out){
    __shared__ __align__(16) ushort inS[14784];   // 4ch x 44rows x 84
    __shared__ __align__(16) ushort wS[8192];     // 32oc x 256
    int img = blockIdx.x >> 1, half = blockIdx.x & 1;
    int tid = threadIdx.x;
    const float4* in4 = (const float4*)(in + (size_t)img*28224);
    for (int i = tid; i < 3696; i += 256){
        int ch = i / 924, rem = i - ch*924;
        int rr = rem / 21, c4 = rem - rr*21;
        float4 v = in4[ch*1764 + (40*half + rr)*21 + c4];
        short4v s; s[0]=(short)f2bf(v.x); s[1]=(short)f2bf(v.y); s[2]=(short)f2bf(v.z); s[3]=(short)f2bf(v.w);
        *(short4v*)&inS[ch*3696 + rr*84 + c4*4] = s;
    }
    for (int i = tid; i < 1024; i += 256)
        *(short8*)&wS[i*8] = *(const short8*)&wb[i*8];
    __syncthreads();
    int w = tid >> 6, lane = tid & 63;
    int n = lane & 31, hi = lane >> 5;
    float bval = bias[n];
    for (int mt = w; mt < 7; mt += 4){
        int p = mt*32 + n; if (p > 199) p = 199;
        int oy = p/20, ox = p - oy*20;            // local oy 0..9
        f32x16 acc = {};
        #pragma unroll
        for (int ks = 0; ks < 16; ks++){
            int kb = ks*16 + hi*8;
            int ic = kb >> 6, r = kb & 63, ky = r >> 3;
            int addr = ic*3696 + (4*oy + ky)*84 + 4*ox;
            short4v lo = *(const short4v*)&inS[addr];
            short4v hh = *(const short4v*)&inS[addr + 4];
            short8 av; av[0]=lo[0];av[1]=lo[1];av[2]=lo[2];av[3]=lo[3];
                       av[4]=hh[0];av[5]=hh[1];av[6]=hh[2];av[7]=hh[3];
            short8 bv = *(const short8*)&wS[n*256 + kb];
            acc = __builtin_amdgcn_mfma_f32_32x32x16_bf16(av, bv, acc, 0,0,0);
        }
        #pragma unroll
        for (int reg = 0; reg < 16; reg++){
            int row = (reg&3) + 8*(reg>>2) + 4*hi;
            int pl = mt*32 + row;
            if (pl < 200){
                int pg = half*200 + pl;
                out[(size_t)img*12800 + n*400 + pg] = fmaxf(acc[reg] + bval, 0.f);
            }
        }
    }
}

// ---------------- conv2: 4x4 s2, 32ch -> 64oc, 20x20 -> 9x9 ----------------
// Block = (img, oc-half). M=81 (pad 96), N=32, K=512 (32 k-steps), k=ky*128+ic*4+kx.
__global__ __launch_bounds__(256) void conv2_mfma(const float* __restrict__ in,   // (480,32,400)
                                                  const ushort* __restrict__ wb,  // (64,512)
                                                  const float* __restrict__ bias,
                                                  float* __restrict__ out){       // (480,64,81)
    __shared__ __align__(16) ushort inS[12800];
    __shared__ __align__(16) ushort wS[16384];    // 32oc x 512
    int img = blockIdx.x >> 1, oh = blockIdx.x & 1;
    int tid = threadIdx.x;
    const float4* in4 = (const float4*)(in + (size_t)img*12800);
    for (int i = tid; i < 3200; i += 256){
        float4 v = in4[i];
        short4v s; s[0]=(short)f2bf(v.x); s[1]=(short)f2bf(v.y); s[2]=(short)f2bf(v.z); s[3]=(short)f2bf(v.w);
        *(short4v*)&inS[i*4] = s;
    }
    const ushort* wsrc = wb + oh*32*512;
    for (int i = tid; i < 2048; i += 256)
        *(short8*)&wS[i*8] = *(const short8*)&wsrc[i*8];
    __syncthreads();
    int w = tid >> 6, lane = tid & 63;
    int n = lane & 31, hi = lane >> 5;
    int noc = oh*32 + n;
    float bval = bias[noc];
    if (w < 3){
        int mt = w;
        int p = mt*32 + n; if (p > 80) p = 80;
        int oy = p/9, ox = p - oy*9;
        f32x16 acc = {};
        for (int ks = 0; ks < 32; ks++){
            int kb = ks*16 + hi*8;
            int ky = kb >> 7, ic0 = (kb & 127) >> 2;
            int base = ic0*400 + (2*oy + ky)*20 + 2*ox;
            short8 av;
            #pragma unroll
            for (int j = 0; j < 8; j++)
                av[j] = (short)inS[base + (j>>2)*400 + (j&3)];
            short8 bv = *(const short8*)&wS[n*512 + kb];
            acc = __builtin_amdgcn_mfma_f32_32x32x16_bf16(av, bv, acc, 0,0,0);
        }
        #pragma unroll
        for (int reg = 0; reg < 16; reg++){
            int row = (reg&3) + 8*(reg>>2) + 4*hi;
            int pl = mt*32 + row;
            if (pl < 81)
                out[(size_t)img*5184 + noc*81 + pl] = fmaxf(acc[reg] + bval, 0.f);
        }
    }
}

// ---------------- conv3: 3x3 s1, 64ch -> 64oc, 9x9 -> 7x7 ----------------
// Block = (img, oc-half). M=49 (pad 64), N=32, K=576 (36 k-steps), k flat (ic,ky,kx).
__global__ __launch_bounds__(256) void conv3_mfma(const float* __restrict__ in,   // (480,64,81)
                                                  const ushort* __restrict__ wb,  // (64,576)
                                                  const float* __restrict__ bias,
                                                  float* __restrict__ out){       // (480,64,49)
    __shared__ __align__(16) ushort inS[5184];
    __shared__ __align__(16) ushort wS[18432];    // 32oc x 576
    int img = blockIdx.x >> 1, oh = blockIdx.x & 1;
    int tid = threadIdx.x;
    const float4* in4 = (const float4*)(in + (size_t)img*5184);
    for (int i = tid; i < 1296; i += 256){
        float4 v = in4[i];
        short4v s; s[0]=(short)f2bf(v.x); s[1]=(short)f2bf(v.y); s[2]=(short)f2bf(v.z); s[3]=(short)f2bf(v.w);
        *(short4v*)&inS[i*4] = s;
    }
    const ushort* wsrc = wb + oh*32*576;
    for (int i = tid; i < 2304; i += 256)
        *(short8*)&wS[i*8] = *(const short8*)&wsrc[i*8];
    __syncthreads();
    int w = tid >> 6, lane = tid & 63;
    int n = lane & 31, hi = lane >> 5;
    int noc = oh*32 + n;
    float bval = bias[noc];
    if (w < 2){
        int mt = w;
        int p = mt*32 + n; if (p > 48) p = 48;
        int oy = p/7, ox = p - oy*7;
        f32x16 acc = {};
        for (int ks = 0; ks < 36; ks++){
            int kb = ks*16 + hi*8;
            short8 av;
            #pragma unroll
            for (int j = 0; j < 8; j++){
                int k = kb + j;
                int ic = k/9, rr = k - ic*9, ky = rr/3, kx = rr - ky*3;
                av[j] = (short)inS[ic*81 + (oy+ky)*9 + ox + kx];
            }
            short8 bv = *(const short8*)&wS[n*576 + kb];
            acc = __builtin_amdgcn_mfma_f32_32x32x16_bf16(av, bv, acc, 0,0,0);
        }
        #pragma unroll
        for (int reg = 0; reg < 16; reg++){
            int row = (reg&3) + 8*(reg>>2) + 4*hi;
            int pl = mt*32 + row;
            if (pl < 49)
                out[(size_t)img*3136 + noc*49 + pl] = fmaxf(acc[reg] + bval, 0.f);
        }
    }
}

// ---------------- Weight prep: fp32 -> bf16 transposed [N][K] ----------------
__global__ __launch_bounds__(256) void prep_fc_emb(const float* __restrict__ fcw,   // (3136,512)
                                                   const float* __restrict__ embw,  // (512,512)
                                                   ushort* __restrict__ fct,        // (512,3136) bf16
                                                   ushort* __restrict__ embt){      // (512,512) bf16
    int idx = blockIdx.x*256 + threadIdx.x;
    const int FCE = 3136*512;
    if (idx < FCE){
        int n = idx / 3136, k = idx - n*3136;
        fct[idx] = f2bf(fcw[(size_t)k*512 + n]);
    } else {
        int r = idx - FCE;
        if (r < 512*512){
            int n = r >> 9, k = r & 511;
            embt[r] = f2bf(embw[(size_t)k*512 + n]);
        }
    }
}

// Per-layer block layout (bf16 elems): [ip_t 1048576 | xp_t 163840 | dt_t 32768 | op_t 524288]
#define WT_PER 1769472
__global__ __launch_bounds__(256) void prep_layers(const float* __restrict__ ipw,  // (L,512,2048)
                                                   const float* __restrict__ xpw,  // (L,1024,160)
                                                   const float* __restrict__ dpw,  // (L,32,1024)
                                                   const float* __restrict__ opw,  // (L,1024,512)
                                                   ushort* __restrict__ wt){
    int idx = blockIdx.x*256 + threadIdx.x;
    if (idx >= 3*WT_PER) return;
    int layer = idx / WT_PER;
    int r = idx - layer*WT_PER;
    ushort* dst = wt + (size_t)layer*WT_PER;
    if (r < 1048576){                       // ip: K=512, N=2048, src stride 2048
        int n = r >> 9, k = r & 511;
        dst[r] = f2bf(ipw[(size_t)layer*1048576 + (size_t)k*2048 + n]);
    } else if (r < 1212416){                // xp: K=1024, N=160, src stride 160
        int q = r - 1048576;
        int n = q >> 10, k = q & 1023;
        dst[r] = f2bf(xpw[(size_t)layer*163840 + (size_t)k*160 + n]);
    } else if (r < 1245184){                // dt: K=32, N=1024, src stride 1024
        int q = r - 1212416;
        int n = q >> 5, k = q & 31;
        dst[r] = f2bf(dpw[(size_t)layer*32768 + (size_t)k*1024 + n]);
    } else {                                // op: K=1024, N=512, src stride 512
        int q = r - 1245184;
        int n = q >> 10, k = q & 1023;
        dst[r] = f2bf(opw[(size_t)layer*524288 + (size_t)k*512 + n]);
    }
}

// ---------------- bf16 MFMA GEMM ----------------
// C[M,N] = epi(A[M,K] (fp32, lda) @ Bt[N,K] (bf16) + bias)
// Block: 256 thr = 4 waves (2x2), tile 64x64, wave tile 32x32, BK=32.
template<bool HAS_BIAS, int ACT, bool ADDC>
__global__ __launch_bounds__(256) void mgemm_kernel(const float* __restrict__ A,
                                                    const ushort* __restrict__ Bt,
                                                    const float* __restrict__ bias,
                                                    float* __restrict__ C,
                                                    int M, int N, int K,
                                                    int lda, int ldc){
    __shared__ __align__(16) ushort As[64][32];
    __shared__ __align__(16) ushort Bs[64][32];
    int bm = blockIdx.y*64, bn = blockIdx.x*64;
    int tid = threadIdx.x;
    int w = tid >> 6, lane = tid & 63;
    int wm = (w >> 1)*32, wn = (w & 1)*32;
    int lr = lane & 15, lg8 = (lane >> 4)*8;
    int sm  = tid >> 2;
    int skq = (tid & 3) * 8;
    int gm = bm + sm;
    int gn = bn + sm;
    bool mok = (gm < M);
    bool nok = (gn < N);
    const float*  arow_p = A  + (size_t)(mok ? gm : 0)*lda + skq;
    const ushort* brow_p = Bt + (size_t)(nok ? gn : 0)*K   + skq;
    f32x4 acc[2][2] = {};
    for (int k0 = 0; k0 < K; k0 += 32){
        short8 av = {0,0,0,0,0,0,0,0};
        if (mok){
            const float* p = arow_p + k0;
            #pragma unroll
            for (int j=0;j<8;j++) av[j] = (short)f2bf(p[j]);
        }
        *reinterpret_cast<short8*>(&As[sm][skq]) = av;
        short8 bv = {0,0,0,0,0,0,0,0};
        if (nok) bv = *reinterpret_cast<const short8*>(brow_p + k0);
        *reinterpret_cast<short8*>(&Bs[sm][skq]) = bv;
        __syncthreads();
        short8 af0 = *reinterpret_cast<const short8*>(&As[wm + lr][lg8]);
        short8 af1 = *reinterpret_cast<const short8*>(&As[wm + 16 + lr][lg8]);
        short8 bf0 = *reinterpret_cast<const short8*>(&Bs[wn + lr][lg8]);
        short8 bf1 = *reinterpret_cast<const short8*>(&Bs[wn + 16 + lr][lg8]);
        acc[0][0] = __builtin_amdgcn_mfma_f32_16x16x32_bf16(af0, bf0, acc[0][0], 0,0,0);
        acc[0][1] = __builtin_amdgcn_mfma_f32_16x16x32_bf16(af0, bf1, acc[0][1], 0,0,0);
        acc[1][0] = __builtin_amdgcn_mfma_f32_16x16x32_bf16(af1, bf0, acc[1][0], 0,0,0);
        acc[1][1] = __builtin_amdgcn_mfma_f32_16x16x32_bf16(af1, bf1, acc[1][1], 0,0,0);
        __syncthreads();
    }
    int lg4 = (lane >> 4) * 4;
    #pragma unroll
    for (int i=0;i<2;i++){
        #pragma unroll
        for (int j=0;j<2;j++){
            int gcol = bn + wn + j*16 + lr;
            if (gcol >= N) continue;
            float bval = HAS_BIAS ? bias[gcol] : 0.f;
            #pragma unroll
            for (int r=0;r<4;r++){
                int grow = bm + wm + i*16 + lg4 + r;
                if (grow >= M) continue;
                float v = acc[i][j][r] + bval;
                if (ACT==1) v = tanhf(v);
                else if (ACT==2) v = (v>20.f)? v : log1pf(__expf(v));
                if (ADDC) C[(size_t)grow*ldc + gcol] += v;
                else      C[(size_t)grow*ldc + gcol] = v;
            }
        }
    }
}

// ---------------- Token build ----------------
__global__ __launch_bounds__(256) void tokens_kernel(const float* __restrict__ rtgs,
                                                     const int* __restrict__ actions,
                                                     const float* __restrict__ state_e,
                                                     const float* __restrict__ ret_w,
                                                     const float* __restrict__ ret_b,
                                                     const float* __restrict__ act_emb,
                                                     float* __restrict__ tok){
    int idx = blockIdx.x*256 + threadIdx.x;            // 1440*512
    if (idx >= NROWS*DMODEL) return;
    int e = idx & (DMODEL-1);
    int row = idx >> 9;
    int rr = row % SEQ; int b = row / SEQ;
    int s = rr % 3, t = rr / 3;
    float v;
    if (s==0)       v = tanhf(rtgs[b*TT+t]*ret_w[e] + ret_b[e]);
    else if (s==1)  v = state_e[(size_t)(b*TT+t)*DMODEL + e];
    else            v = tanhf(act_emb[(size_t)actions[b*TT+t]*DMODEL + e]);
    tok[idx] = v;
}

// ---------------- RMSNorm (block per row) ----------------
__global__ __launch_bounds__(256) void rmsnorm_kernel(const float* __restrict__ x,
                                                      const float* __restrict__ w,
                                                      float* __restrict__ o){
    int row = blockIdx.x;
    int tid = threadIdx.x;
    float v0 = x[(size_t)row*DMODEL + tid];
    float v1 = x[(size_t)row*DMODEL + 256 + tid];
    float s = v0*v0 + v1*v1;
    for (int off=32; off; off>>=1) s += __shfl_xor(s, off, 64);
    __shared__ float wsum[4];
    if ((tid&63)==0) wsum[tid>>6] = s;
    __syncthreads();
    s = wsum[0]+wsum[1]+wsum[2]+wsum[3];
    float scale = rsqrtf(s*(1.f/DMODEL) + 1e-5f);
    o[(size_t)row*DMODEL + tid]       = v0*scale*w[tid];
    o[(size_t)row*DMODEL + 256 + tid] = v1*scale*w[256+tid];
}

// final norm: only state-token rows (b*90 + 3t + 1) -> xf[480 rows]
__global__ __launch_bounds__(256) void rmsnorm_final_kernel(const float* __restrict__ x,
                                                            const float* __restrict__ w,
                                                            float* __restrict__ o){
    int r = blockIdx.x;              // 0..479 = b*30+t
    int b = r / TT, t = r % TT;
    int src = b*SEQ + 3*t + 1;
    int tid = threadIdx.x;
    float v0 = x[(size_t)src*DMODEL + tid];
    float v1 = x[(size_t)src*DMODEL + 256 + tid];
    float s = v0*v0 + v1*v1;
    for (int off=32; off; off>>=1) s += __shfl_xor(s, off, 64);
    __shared__ float wsum[4];
    if ((tid&63)==0) wsum[tid>>6] = s;
    __syncthreads();
    s = wsum[0]+wsum[1]+wsum[2]+wsum[3];
    float scale = rsqrtf(s*(1.f/DMODEL) + 1e-5f);
    o[(size_t)r*DMODEL + tid]       = v0*scale*w[tid];
    o[(size_t)r*DMODEL + 256 + tid] = v1*scale*w[256+tid];
}

// ---------------- Depthwise causal conv (K=4) + SiLU, IN-PLACE on xs half of xz ----------------
__global__ __launch_bounds__(256) void dwconv_silu_inplace(float* __restrict__ xz,
                                                           const float* __restrict__ cw,
                                                           const float* __restrict__ cb){
    int idx = blockIdx.x*256 + threadIdx.x;            // 16*1024
    if (idx >= BB*DINNER) return;
    int d = idx & (DINNER-1);
    int b = idx >> 10;
    float w0 = cw[d*4+0], w1 = cw[d*4+1], w2 = cw[d*4+2], w3 = cw[d*4+3];
    float bias = cb[d];
    float xm3 = 0.f, xm2 = 0.f, xm1 = 0.f;
    float* p = xz + (size_t)(b*SEQ)*(2*DINNER) + d;
    for (int t=0;t<SEQ;t++){
        float cur = p[(size_t)t*(2*DINNER)];
        float acc = bias + w0*xm3 + w1*xm2 + w2*xm1 + w3*cur;
        p[(size_t)t*(2*DINNER)] = acc*sigmoidf_(acc);
        xm3 = xm2; xm2 = xm1; xm1 = cur;
    }
}

// ---------------- Selective scan (one wave per (b,d), lane = n), y in-place over delta ----------------
__global__ __launch_bounds__(64) void scan_kernel(float* delta_y,                  // (1440,1024) in: delta, out: y
                                                  const float* __restrict__ xz,    // (1440,2048)
                                                  const float* __restrict__ xdbl,  // (1440,160)
                                                  const float* __restrict__ alog,  // (1024,64)
                                                  const float* __restrict__ Dp){   // (1024)
    int blk = blockIdx.x;            // 16*1024
    int d = blk & (DINNER-1);
    int b = blk >> 10;
    int lane = threadIdx.x;
    float A = -__expf(alog[(size_t)d*NSTATE + lane]);
    float Dv = Dp[d];
    float h = 0.f;
    int base = b*SEQ;
    for (int t=0;t<SEQ;t++){
        int row = base + t;
        float dt = delta_y[(size_t)row*DINNER + d];
        float uu = xz[(size_t)row*(2*DINNER) + d];
        float Bv = xdbl[row*160 + DTRANK + lane];
        float Cv = xdbl[row*160 + DTRANK + NSTATE + lane];
        float dA = __expf(dt*A);
        h = dA*h + dt*uu*Bv;
        float p = h*Cv;
        #pragma unroll
        for (int off=32; off; off>>=1) p += __shfl_xor(p, off, 64);
        if (lane==0){
            float res = xz[(size_t)row*(2*DINNER) + DINNER + d];
            delta_y[(size_t)row*DINNER + d] = (p + uu*Dv) * (res*sigmoidf_(res));
        }
    }
}

// ---------------- Head: logits for state-token rows ----------------
__global__ __launch_bounds__(256) void head_kernel(const float* __restrict__ xf,   // (480,512)
                                                   const float* __restrict__ hw,   // (512,18)
                                                   float* __restrict__ out){       // (480,18)
    int idx = blockIdx.x*256 + threadIdx.x;
    if (idx >= BT*NVOCAB) return;
    int col = idx % NVOCAB, r = idx / NVOCAB;
    const float* xr = xf + (size_t)r*DMODEL;
    float acc = 0.f;
    for (int k=0;k<DMODEL;k++) acc += xr[k]*hw[k*NVOCAB+col];
    out[idx] = acc;
}

extern "C" void kernel_launch(void* const* d_in, const int* in_sizes, int n_in,
                              void* d_out, int out_size, void* d_ws, size_t ws_size,
                              hipStream_t stream) {
    const float* states = (const float*)d_in[0];
    const int*   actions= (const int*)d_in[1];
    const float* rtgs   = (const float*)d_in[2];
    const float* c1w = (const float*)d_in[3];
    const float* c1b = (const float*)d_in[4];
    const float* c2w = (const float*)d_in[5];
    const float* c2b = (const float*)d_in[6];
    const float* c3w = (const float*)d_in[7];
    const float* c3b = (const float*)d_in[8];
    const float* fcw = (const float*)d_in[9];
    const float* fcb = (const float*)d_in[10];
    const float* retw= (const float*)d_in[11];
    const float* retb= (const float*)d_in[12];
    const float* actemb=(const float*)d_in[13];
    const float* embw= (const float*)d_in[14];
    const float* embb= (const float*)d_in[15];
    const float* normw=(const float*)d_in[16];
    const float* ipw = (const float*)d_in[17];
    const float* cw  = (const float*)d_in[18];
    const float* cb  = (const float*)d_in[19];
    const float* xpw = (const float*)d_in[20];
    const float* dpw = (const float*)d_in[21];
    const float* dpb = (const float*)d_in[22];
    const float* alog= (const float*)d_in[23];
    const float* Dp  = (const float*)d_in[24];
    const float* opw = (const float*)d_in[25];
    const float* normfw=(const float*)d_in[26];
    const float* headw= (const float*)d_in[27];
    float* out = (float*)d_out;

    float* ws = (float*)d_ws;
    // ---- Workspace map (float offsets). TOTAL = 10,307,584 floats = 41.23 MB,
    //      UNDER the round-2-proven ws bound of 10,383,360 floats. ----
    ushort* wt  = (ushort*)(ws + 0);         // [0, 2,654,208)  3*WT_PER bf16
    float* x    = ws + 2654208;
    float* xn   = ws + 3391488;              // (tok/xf share)
    float* tok  = ws + 3391488;
    float* xf   = ws + 3391488;
    float* xz   = ws + 4128768;
    float* xdbl = ws + 7077888;
    float* delta= ws + 7308288;
    // Encoder-phase overlays:
    float* c1   = ws + 0;                    // [0, 6,144,000)          dead after conv2
    float* c2   = ws + 6144000;              // [6,144,000, 8,632,320)  dead after conv3
    float* c3   = ws + 8632320;              // [8,632,320, 10,137,600) dead after FC gemm
    ushort* fct  = (ushort*)(ws + 2654208);  // in dead-c1, dead after FC gemm
    ushort* embt = (ushort*)(ws + 10137600); // [10,137,600, 10,268,672)
    float* se   = ws + 4128768;              // xz slot, dead after tokens
    // Conv bf16 weights (persistent through encoder):
    ushort* c1wb = (ushort*)(ws + 10268672); //  8192 us -> [10,268,672, 10,272,768)
    ushort* c2wb = (ushort*)(ws + 10272768); // 32768 us -> [10,272,768, 10,289,152)
    ushort* c3wb = (ushort*)(ws + 10289152); // 36864 us -> [10,289,152, 10,307,584)

    // ---- conv weight prep, then encoder (MFMA convs) ----
    prep_convw<<<304, 256, 0, stream>>>(c1w, c2w, c3w, c1wb, c2wb, c3wb);
    conv1_mfma<<<960, 256, 0, stream>>>(states, c1wb, c1b, c1);
    conv2_mfma<<<960, 256, 0, stream>>>(c1, c2wb, c2b, c2);
    // c1 dead: prep main weights into its region
    prep_fc_emb<<<(3136*512 + 512*512 + 255)/256, 256, 0, stream>>>(fcw, embw, fct, embt);
    prep_layers<<<(3*WT_PER+255)/256, 256, 0, stream>>>(ipw, xpw, dpw, opw, wt);
    conv3_mfma<<<960, 256, 0, stream>>>(c2, c3wb, c3b, c3);
    // FC + tanh : (480,3136)@(3136,512)
    mgemm_kernel<true,1,false><<<dim3(8,8), 256, 0, stream>>>(c3, fct, fcb, se,
                                                              BT, DMODEL, 3136, 3136, DMODEL);
    // ---- tokens + embedding ----
    tokens_kernel<<<(NROWS*DMODEL+255)/256, 256, 0, stream>>>(rtgs, actions, se, retw, retb, actemb, tok);
    mgemm_kernel<true,0,false><<<dim3(8,23), 256, 0, stream>>>(tok, embt, embb, x,
                                                               NROWS, DMODEL, DMODEL, DMODEL, DMODEL);
    // ---- mamba layers ----
    for (int i=0;i<3;i++){
        const ushort* wl = wt + (size_t)i*WT_PER;
        rmsnorm_kernel<<<NROWS, 256, 0, stream>>>(x, normw + (size_t)i*DMODEL, xn);
        mgemm_kernel<false,0,false><<<dim3(32,23), 256, 0, stream>>>(xn, wl, nullptr, xz,
                                                                     NROWS, 2*DINNER, DMODEL, DMODEL, 2*DINNER);
        dwconv_silu_inplace<<<(BB*DINNER+255)/256, 256, 0, stream>>>(xz, cw + (size_t)i*DINNER*4, cb + (size_t)i*DINNER);
        mgemm_kernel<false,0,false><<<dim3(3,23), 256, 0, stream>>>(xz, wl + 1048576, nullptr, xdbl,
                                                                    NROWS, 160, DINNER, 2*DINNER, 160);
        mgemm_kernel<true,2,false><<<dim3(16,23), 256, 0, stream>>>(xdbl, wl + 1212416, dpb + (size_t)i*DINNER, delta,
                                                                    NROWS, DINNER, DTRANK, 160, DINNER);
        scan_kernel<<<BB*DINNER, 64, 0, stream>>>(delta, xz, xdbl,
                                                  alog + (size_t)i*DINNER*NSTATE,
                                                  Dp + (size_t)i*DINNER);
        mgemm_kernel<false,0,true><<<dim3(8,23), 256, 0, stream>>>(delta, wl + 1245184, nullptr, x,
                                                                   NROWS, DMODEL, DINNER, DINNER, DMODEL);
    }
    // ---- final norm (state rows only) + head ----
    rmsnorm_final_kernel<<<BT, 256, 0, stream>>>(x, normfw, xf);
    head_kernel<<<(BT*NVOCAB+255)/256, 256, 0, stream>>>(xf, headw, out);
}